// Round 16
// baseline (302.930 us; speedup 1.0000x reference)
//
#include <hip/hip_runtime.h>

typedef float f32x4 __attribute__((ext_vector_type(4)));
typedef _Float16 h8 __attribute__((ext_vector_type(8)));
typedef unsigned short us8 __attribute__((ext_vector_type(8)));

#define DEV __device__ __forceinline__

constexpr int Bb = 32, Nn = 1024, Mm = 576, Dd = 768;
constexpr float L2E = 1.44269504088896340736f;

// ws layout (ushort elems), fragment-major for 16x16x32 f16 MFMA:
//   Kf: [b][kvtile 36][dc 24][lane 64][8]   B-frag: K[kvt*16+(l&15)][dc*32+(l>>4)*8+j]
//   Vf: [b][kc 18][dtile 48][lane 64][8]    B-frag: V[kc*32+(l>>4)*8+j][dt*16+(l&15)]
constexpr size_t KF_ELEMS = (size_t)Bb * 36 * 24 * 512;  // 14,155,776

DEV unsigned short f2h(float x) {
  _Float16 h = (_Float16)x;
  return __builtin_bit_cast(unsigned short, h);
}
DEV void gll16(const void* g, void* l) {
  __builtin_amdgcn_global_load_lds(
      (const __attribute__((address_space(1))) void*)g,
      (__attribute__((address_space(3))) void*)l, 16, 0, 0);
}

// ---------------- pre-pass: K -> Kf, Vf (fragment-major f16) — unchanged
__global__ __launch_bounds__(256)
void fusion_prep(const float* __restrict__ K, unsigned short* __restrict__ Kf,
                 unsigned short* __restrict__ Vf)
{
  const int t = threadIdx.x;
  const int b = blockIdx.x / 24, dc = blockIdx.x % 24;
  const int l = t & 63;
  {
    const int lt = t >> 6;
    const int ro = l & 15, go = l >> 4;
#pragma unroll
    for (int it = 0; it < 9; ++it) {
      const int kvt = it * 4 + lt;
      const float* src = K + ((size_t)(b * Mm + kvt * 16 + ro)) * Dd + dc * 32 + go * 8;
      f32x4 v0 = *(const f32x4*)src;
      f32x4 v1 = *(const f32x4*)(src + 4);
      us8 h;
      h[0]=f2h(v0[0]); h[1]=f2h(v0[1]); h[2]=f2h(v0[2]); h[3]=f2h(v0[3]);
      h[4]=f2h(v1[0]); h[5]=f2h(v1[1]); h[6]=f2h(v1[2]); h[7]=f2h(v1[3]);
      *(us8*)&Kf[(((size_t)((b * 36 + kvt) * 24 + dc)) << 9) + l * 8] = h;
    }
  }
  {
    const int kch = t >> 7;
    const int dtl = (t >> 6) & 1;
    const int d = dc * 32 + dtl * 16 + (l & 15);
    const int kvo = (l >> 4) * 8;
#pragma unroll
    for (int it = 0; it < 9; ++it) {
      const int kc = it * 2 + kch;
      const int kv0 = kc * 32 + kvo;
      us8 o;
#pragma unroll
      for (int j = 0; j < 8; ++j)
        o[j] = f2h(K[((size_t)(b * Mm + kv0 + j)) * Dd + d]);
      *(us8*)&Vf[(((size_t)((b * 18 + kc) * 48 + dc * 2 + dtl)) << 9) + l * 8] = o;
    }
  }
}

// ---------------- main: BK=64 (2 chunks per barrier, 12 iters), Q in registers.
// LDS (bytes): bufK2[2] @ {0, 73728} (each = 2 chunks x 36 KB). No Q LDS.
//              sP (128x576 f16, pitch 1152 B, XOR swizzle) aliases 0..147456 after QK
__global__ __launch_bounds__(1024, 1)
void fusion_main(const float* __restrict__ Q, const unsigned short* __restrict__ Kf,
                 const unsigned short* __restrict__ Vf, float* __restrict__ Out)
{
  __shared__ alignas(16) unsigned char lds[147456];
  __shared__ float sRa[4][128];
  __shared__ float sRb[4][128];

  const int tid  = threadIdx.x;
  const int lane = tid & 63;
  const int w    = tid >> 6;      // 0..15
  const int g    = lane >> 4;
  const int ln   = lane & 15;
  const int wq   = w >> 2;        // QK: 0..3, q rows [wq*32,+32)
  const int wkv  = w & 3;         // QK: kv slice [wkv*144,+144)
  const int wq2  = w >> 3;        // PV: 0..1
  const int wd8  = w & 7;         // PV: d slice [wd8*96,+96)

  // XCD swizzle
  const int bid = blockIdx.x;
  const int xcd = bid & 7, ii = bid >> 3;
  const int b  = (xcd << 2) | (ii >> 3);
  const int q0 = (ii & 7) * 128;

  const float* Qb = Q + ((size_t)(b * Nn + q0)) * Dd;
  const unsigned char* KfB = (const unsigned char*)Kf + ((size_t)(b * 36 * 24) << 10);
  const unsigned short* VfB = Vf + ((size_t)(b * 18 * 48) << 9);

  // K staging: 72 one-KB units per iteration over 16 waves (8x5 + 8x4)
  const int nu = (w < 8) ? 5 : 4;
  const int u0 = (w < 8) ? w * 5 : 40 + (w - 8) * 4;

  // Q self-load pointers: row wq*32 + mt*16 + ln, cols g*8 (+4); iter i adds i*64 + cc*32
  const float* qp[2];
  qp[0] = Qb + (size_t)(wq * 32 + ln) * Dd + g * 8;
  qp[1] = qp[0] + (size_t)16 * Dd;

  // ---------------- prologue: stage chunks 0,1 -> buf0 (chunk-major); Q(iter0) -> regs
  f32x4 qvA[2][2][2], qvB[2][2][2];
#pragma unroll
  for (int mt = 0; mt < 2; ++mt)
#pragma unroll
    for (int cc = 0; cc < 2; ++cc) {
      qvA[mt][cc][0] = *(const f32x4*)(qp[mt] + cc * 32);
      qvA[mt][cc][1] = *(const f32x4*)(qp[mt] + cc * 32 + 4);
    }
#pragma unroll
  for (int j = 0; j < 5; ++j)
    if (j < nu) {
      const int u = u0 + j;
      const int cc = u / 36, uu = u % 36;
      gll16(KfB + ((size_t)(uu * 24 + cc) << 10) + (lane << 4),
            lds + cc * 36864 + uu * 1024);
    }
  __syncthreads();

  // ---------------- QK loop: 12 iterations, 2 chunks each, 1 barrier per iter
  f32x4 acc[2][9];
#pragma unroll
  for (int mt = 0; mt < 2; ++mt)
#pragma unroll
    for (int nt = 0; nt < 9; ++nt) acc[mt][nt] = (f32x4){0.f, 0.f, 0.f, 0.f};

#pragma unroll 1
  for (int i = 0; i < 12; ++i) {
    const bool stg = (i < 11);
    // issue next iter's Q loads + K stages (land under this iter's compute)
    if (stg) {
#pragma unroll
      for (int mt = 0; mt < 2; ++mt)
#pragma unroll
        for (int cc = 0; cc < 2; ++cc) {
          const size_t off = (size_t)(i + 1) * 64 + cc * 32;
          qvB[mt][cc][0] = *(const f32x4*)(qp[mt] + off);
          qvB[mt][cc][1] = *(const f32x4*)(qp[mt] + off + 4);
        }
      unsigned char* dstb = lds + ((i + 1) & 1) * 73728;
#pragma unroll
      for (int j = 0; j < 5; ++j)
        if (j < nu) {
          const int u = u0 + j;
          const int cc = u / 36, uu = u % 36;
          gll16(KfB + ((size_t)(uu * 24 + 2 * i + 2 + cc) << 10) + (lane << 4),
                dstb + cc * 36864 + uu * 1024);
        }
    }
    // compute both chunks of this iter from buf[i&1]
    const unsigned char* kbb = lds + (i & 1) * 73728;
#pragma unroll
    for (int cc = 0; cc < 2; ++cc) {
      h8 qh[2];
#pragma unroll
      for (int mt = 0; mt < 2; ++mt)
#pragma unroll
        for (int k = 0; k < 4; ++k) {
          qh[mt][k]     = (_Float16)(qvA[mt][cc][0][k] * L2E);
          qh[mt][k + 4] = (_Float16)(qvA[mt][cc][1][k] * L2E);
        }
      const unsigned char* kb = kbb + cc * 36864;
      __builtin_amdgcn_s_setprio(1);
#pragma unroll
      for (int nt = 0; nt < 9; ++nt) {
        const h8 kf = *(const h8*)(kb + (wkv * 9 + nt) * 1024 + lane * 16);
#pragma unroll
        for (int mt = 0; mt < 2; ++mt)
          acc[mt][nt] = __builtin_amdgcn_mfma_f32_16x16x32_f16(qh[mt], kf, acc[mt][nt], 0, 0, 0);
      }
      __builtin_amdgcn_s_setprio(0);
    }
    // rotate Q regs
    if (stg) {
#pragma unroll
      for (int mt = 0; mt < 2; ++mt)
#pragma unroll
        for (int cc = 0; cc < 2; ++cc) {
          qvA[mt][cc][0] = qvB[mt][cc][0];
          qvA[mt][cc][1] = qvB[mt][cc][1];
        }
    }
    __syncthreads();   // full drain: next iter's buf + this iter's reads ordered
  }

  // ---------------- one-shot softmax (exp2 domain; Q pre-scaled by log2 e)
  float pm[2][4];
#pragma unroll
  for (int mt = 0; mt < 2; ++mt)
#pragma unroll
    for (int i2 = 0; i2 < 4; ++i2) {
      float v = acc[mt][0][i2];
#pragma unroll
      for (int nt = 1; nt < 9; ++nt) v = fmaxf(v, acc[mt][nt][i2]);
      pm[mt][i2] = v;
    }
#pragma unroll
  for (int mk = 1; mk < 16; mk <<= 1)
#pragma unroll
    for (int mt = 0; mt < 2; ++mt)
#pragma unroll
      for (int i2 = 0; i2 < 4; ++i2)
        pm[mt][i2] = fmaxf(pm[mt][i2], __shfl_xor(pm[mt][i2], mk, 64));
  if (ln == 0) {
#pragma unroll
    for (int mt = 0; mt < 2; ++mt)
#pragma unroll
      for (int i2 = 0; i2 < 4; ++i2)
        sRa[wkv][wq * 32 + mt * 16 + g * 4 + i2] = pm[mt][i2];
  }
  __syncthreads();

  float mfin[2][4], ps[2][4];
#pragma unroll
  for (int mt = 0; mt < 2; ++mt)
#pragma unroll
    for (int i2 = 0; i2 < 4; ++i2) {
      const int rw = wq * 32 + mt * 16 + g * 4 + i2;
      mfin[mt][i2] = fmaxf(fmaxf(sRa[0][rw], sRa[1][rw]), fmaxf(sRa[2][rw], sRa[3][rw]));
      ps[mt][i2] = 0.f;
    }
#pragma unroll
  for (int mt = 0; mt < 2; ++mt)
#pragma unroll
    for (int nt = 0; nt < 9; ++nt)
#pragma unroll
      for (int i2 = 0; i2 < 4; ++i2) {
        const float p = exp2f(acc[mt][nt][i2] - mfin[mt][i2]);
        acc[mt][nt][i2] = p;
        ps[mt][i2] += p;
      }
#pragma unroll
  for (int mk = 1; mk < 16; mk <<= 1)
#pragma unroll
    for (int mt = 0; mt < 2; ++mt)
#pragma unroll
      for (int i2 = 0; i2 < 4; ++i2)
        ps[mt][i2] += __shfl_xor(ps[mt][i2], mk, 64);
  if (ln == 0) {
#pragma unroll
    for (int mt = 0; mt < 2; ++mt)
#pragma unroll
      for (int i2 = 0; i2 < 4; ++i2)
        sRb[wkv][wq * 32 + mt * 16 + g * 4 + i2] = ps[mt][i2];
  }
  __syncthreads();

  // normalize P -> swizzled sP (aliases dead bufK)
  {
    unsigned short* sPp = (unsigned short*)lds;
#pragma unroll
    for (int mt = 0; mt < 2; ++mt)
#pragma unroll
      for (int i2 = 0; i2 < 4; ++i2) {
        const int rw = wq * 32 + mt * 16 + g * 4 + i2;
        const float inv = 1.0f / ((sRb[0][rw] + sRb[1][rw]) + (sRb[2][rw] + sRb[3][rw]));
#pragma unroll
        for (int nt = 0; nt < 9; ++nt) {
          const int u = wkv * 18 + nt * 2 + (ln >> 3);
          sPp[rw * 576 + ((u ^ (rw & 7)) << 3) + (ln & 7)] = f2h(acc[mt][nt][i2] * inv);
        }
      }
  }
  __syncthreads();

  // ---------------- PV: [64q x 96d]/wave x 2 passes; vf double-buffered (2x unroll)
#pragma unroll 1
  for (int p = 0; p < 2; ++p) {
    f32x4 O[4][3];
#pragma unroll
    for (int mt = 0; mt < 4; ++mt)
#pragma unroll
      for (int nt = 0; nt < 3; ++nt) O[mt][nt] = (f32x4){0.f, 0.f, 0.f, 0.f};

    // dtile base: dt = wd8*6 + p*3 + nt
    const unsigned short* vbase = VfB + ((size_t)(wd8 * 6 + p * 3) << 9) + lane * 8;
    h8 vfA[3], vfB2[3];
#pragma unroll
    for (int nt = 0; nt < 3; ++nt)
      vfA[nt] = *(const h8*)(vbase + ((size_t)nt << 9));

#pragma unroll 1
    for (int kc = 0; kc < 18; kc += 2) {
#pragma unroll
      for (int nt = 0; nt < 3; ++nt)
        vfB2[nt] = *(const h8*)(vbase + ((size_t)((kc + 1) * 48 + nt) << 9));
      {
        h8 pa[4];
#pragma unroll
        for (int mt = 0; mt < 4; ++mt) {
          const int row = wq2 * 64 + mt * 16 + ln;
          const int u = kc * 4 + g;
          pa[mt] = *(const h8*)(lds + row * 1152 + ((u ^ (row & 7)) << 4));
        }
#pragma unroll
        for (int nt = 0; nt < 3; ++nt)
#pragma unroll
          for (int mt = 0; mt < 4; ++mt)
            O[mt][nt] = __builtin_amdgcn_mfma_f32_16x16x32_f16(pa[mt], vfA[nt], O[mt][nt], 0, 0, 0);
      }
      if (kc < 16) {
#pragma unroll
        for (int nt = 0; nt < 3; ++nt)
          vfA[nt] = *(const h8*)(vbase + ((size_t)((kc + 2) * 48 + nt) << 9));
      }
      {
        h8 pa[4];
#pragma unroll
        for (int mt = 0; mt < 4; ++mt) {
          const int row = wq2 * 64 + mt * 16 + ln;
          const int u = (kc + 1) * 4 + g;
          pa[mt] = *(const h8*)(lds + row * 1152 + ((u ^ (row & 7)) << 4));
        }
#pragma unroll
        for (int nt = 0; nt < 3; ++nt)
#pragma unroll
          for (int mt = 0; mt < 4; ++mt)
            O[mt][nt] = __builtin_amdgcn_mfma_f32_16x16x32_f16(pa[mt], vfB2[nt], O[mt][nt], 0, 0, 0);
      }
    }

    float* ob = Out + ((size_t)(b * Nn + q0 + wq2 * 64)) * Dd;
#pragma unroll
    for (int mt = 0; mt < 4; ++mt)
#pragma unroll
      for (int nt = 0; nt < 3; ++nt)
#pragma unroll
        for (int i2 = 0; i2 < 4; ++i2)
          ob[(size_t)(mt * 16 + g * 4 + i2) * Dd + wd8 * 96 + p * 48 + nt * 16 + ln] = O[mt][nt][i2];
  }
}

extern "C" void kernel_launch(void* const* d_in, const int* in_sizes, int n_in,
                              void* d_out, int out_size, void* d_ws, size_t ws_size,
                              hipStream_t stream) {
  const float* Q = (const float*)d_in[0];
  const float* K = (const float*)d_in[1];
  float* Out = (float*)d_out;
  unsigned short* Kf = (unsigned short*)d_ws;
  unsigned short* Vf = Kf + KF_ELEMS;
  fusion_prep<<<dim3(Bb * 24), dim3(256), 0, stream>>>(K, Kf, Vf);
  fusion_main<<<dim3(Bb * 8), dim3(1024), 0, stream>>>(Q, Kf, Vf, Out);
}

// Round 17
// 111.948 us; speedup vs baseline: 2.7060x; 2.7060x over previous
//
#include <hip/hip_runtime.h>

typedef float f32x4 __attribute__((ext_vector_type(4)));
typedef _Float16 h8 __attribute__((ext_vector_type(8)));
typedef unsigned short us8 __attribute__((ext_vector_type(8)));

#define DEV __device__ __forceinline__
#define SBARRIER() asm volatile("s_barrier" ::: "memory")
#define LGKM0()    asm volatile("s_waitcnt lgkmcnt(0)" ::: "memory")
#define VMCNT3()   asm volatile("s_waitcnt vmcnt(3)" ::: "memory")
#define VMCNT0()   asm volatile("s_waitcnt vmcnt(0)" ::: "memory")
#define SCHED0()   __builtin_amdgcn_sched_barrier(0)

constexpr int Bb = 32, Nn = 1024, Mm = 576, Dd = 768;
constexpr float L2E = 1.44269504088896340736f;

// ws layout (ushort elems), fragment-major for 16x16x32 f16 MFMA:
//   Kf: [b][kvtile 36][dc 24][lane 64][8]   B-frag: K[kvt*16+(l&15)][dc*32+(l>>4)*8+j]
//   Vf: [b][kc 18][dtile 48][lane 64][8]    B-frag: V[kc*32+(l>>4)*8+j][dt*16+(l&15)]
constexpr size_t KF_ELEMS = (size_t)Bb * 36 * 24 * 512;  // 14,155,776

DEV unsigned short f2h(float x) {
  _Float16 h = (_Float16)x;
  return __builtin_bit_cast(unsigned short, h);
}
DEV void gll16(const void* g, void* l) {
  __builtin_amdgcn_global_load_lds(
      (const __attribute__((address_space(1))) void*)g,
      (__attribute__((address_space(3))) void*)l, 16, 0, 0);
}

// ---------------- pre-pass (REWRITTEN): K read ONCE, LDS-staged, both outputs coalesced.
// block = (b, rowtile rt of 64 kv rows, dc half). Per dc chunk: stage K[64][32] -> ks,
// then emit 4 Kf frags (rows of ks) + 4 Vf frags (cols of ks). [64][33] pad: no conflicts.
__global__ __launch_bounds__(256)
void fusion_prep(const float* __restrict__ K, unsigned short* __restrict__ Kf,
                 unsigned short* __restrict__ Vf)
{
  __shared__ float ks[64][33];
  const int t   = threadIdx.x;
  const int blk = blockIdx.x;
  const int b    = blk / 18;
  const int r2   = blk % 18;
  const int rt   = r2 >> 1;        // 0..8 : kv rows [rt*64, +64)
  const int half = r2 & 1;         // dc in [half*12, +12)
  const int l    = t & 63;

  // stage mapping: 2 f32x4 per thread
  const int row0 = t >> 3, c40 = t & 7;          // idx = t
  const int row1 = (t + 256) >> 3;               // idx = t + 256
  const float* Kb = K + ((size_t)(b * Mm + rt * 64)) * Dd;

  // Kf mapping: kvt_l = t>>6, lane l
  const int kvt_l = t >> 6;
  const int kf_r  = kvt_l * 16 + (l & 15);
  const int kf_c  = (l >> 4) * 8;
  // Vf mapping: kc_l = t>>7, dtl = (t>>6)&1, lane l
  const int kc_l = t >> 7;
  const int dtl  = (t >> 6) & 1;
  const int vf_r = kc_l * 32 + (l >> 4) * 8;
  const int vf_c = dtl * 16 + (l & 15);

#pragma unroll 1
  for (int dc = half * 12; dc < half * 12 + 12; ++dc) {
    __syncthreads();   // previous iteration's reads of ks done
    f32x4 v0 = *(const f32x4*)(Kb + (size_t)row0 * Dd + dc * 32 + c40 * 4);
    f32x4 v1 = *(const f32x4*)(Kb + (size_t)row1 * Dd + dc * 32 + c40 * 4);
    *(f32x4*)&ks[row0][c40 * 4] = v0;   // [64][33] pad: scalar-ish store ok (33 not 16B-aligned)
    *(f32x4*)&ks[row1][c40 * 4] = v1;
    __syncthreads();
    // Kf: rows of ks
    {
      us8 h;
#pragma unroll
      for (int j = 0; j < 8; ++j) h[j] = f2h(ks[kf_r][kf_c + j]);
      *(us8*)&Kf[(((size_t)((b * 36 + rt * 4 + kvt_l) * 24 + dc)) << 9) + l * 8] = h;
    }
    // Vf: cols of ks
    {
      us8 o;
#pragma unroll
      for (int j = 0; j < 8; ++j) o[j] = f2h(ks[vf_r + j][vf_c]);
      *(us8*)&Vf[(((size_t)((b * 18 + rt * 2 + kc_l) * 48 + dc * 2 + dtl)) << 9) + l * 8] = o;
    }
  }
}

// ---------------- main: R15 EXACT (best proven 119.66 us) — R13 structure + lb(1024,1)
// LDS (bytes): bufK[3] @ {0,36864,73728}; qbuf[2] @ 110592+{0,8192} (hi only)
//              sP (128x576 f16, pitch 1152 B, XOR swizzle) aliases 0..147456 after QK
__global__ __launch_bounds__(1024, 1)
void fusion_main(const float* __restrict__ Q, const unsigned short* __restrict__ Kf,
                 const unsigned short* __restrict__ Vf, float* __restrict__ Out)
{
  __shared__ alignas(16) unsigned char lds[147456];
  __shared__ float sRa[4][128];
  __shared__ float sRb[4][128];

  const int tid  = threadIdx.x;
  const int lane = tid & 63;
  const int w    = tid >> 6;      // 0..15
  const int g    = lane >> 4;
  const int ln   = lane & 15;
  const int wq   = w >> 2;        // QK: 0..3, q rows [wq*32,+32)
  const int wkv  = w & 3;         // QK: kv slice [wkv*144,+144)
  const int wq2  = w >> 3;        // PV: 0..1
  const int wd8  = w & 7;         // PV: d slice [wd8*96,+96)

  const bool loader  = (w < 12);  // 3 gll16/chunk, no other vmem in QK loop
  const bool qstager = (w >= 12); // 2 f32x4 Q loads + cvt + ds_write, no gll16

  // XCD swizzle
  const int bid = blockIdx.x;
  const int xcd = bid & 7, ii = bid >> 3;
  const int b  = (xcd << 2) | (ii >> 3);
  const int q0 = (ii & 7) * 128;

  const float* Qb = Q + ((size_t)(b * Nn + q0)) * Dd;
  const unsigned char* KfB = (const unsigned char*)Kf + ((size_t)(b * 36 * 24) << 10);
  const unsigned short* VfB = Vf + ((size_t)(b * 18 * 48) << 9);

  // loader constants: units u0..u0+2 of 36 (1 KB each)
  const int u0 = w * 3;
  // qstager constants: 2 slots, slot s: qt=s>>6, l=s&63
  const int t256 = tid & 255;
  const int s0 = t256, s1 = t256 + 256;
  const int qt0 = s0 >> 6, l0 = s0 & 63;
  const int qt1 = s1 >> 6, l1 = s1 & 63;
  const float* qsrc0 = Qb + (size_t)(qt0 * 16 + (l0 & 15)) * Dd + (l0 >> 4) * 8;
  const float* qsrc1 = Qb + (size_t)(qt1 * 16 + (l1 & 15)) * Dd + (l1 >> 4) * 8;
  unsigned char* qd0 = lds + 110592 + qt0 * 1024 + l0 * 16;
  unsigned char* qd1 = lds + 110592 + qt1 * 1024 + l1 * 16;

  // ---------------- prologue
  {
    f32x4 a0, a1, b0, b1;
    if (qstager) {
      a0 = *(const f32x4*)qsrc0; a1 = *(const f32x4*)(qsrc0 + 4);
      b0 = *(const f32x4*)qsrc1; b1 = *(const f32x4*)(qsrc1 + 4);
    }
    SCHED0();
    if (loader) {
      // CHUNK-MAJOR issue order: all of K(0), then all of K(1) ->
      // VMCNT3 below guarantees K(0) fully landed, K(1) in flight.
#pragma unroll
      for (int j = 0; j < 3; ++j)
        gll16(KfB + ((size_t)((u0 + j) * 24) << 10) + (lane << 4), lds + (u0 + j) * 1024);
#pragma unroll
      for (int j = 0; j < 3; ++j)
        gll16(KfB + ((size_t)((u0 + j) * 24 + 1) << 10) + (lane << 4), lds + 36864 + (u0 + j) * 1024);
    }
    if (qstager) {
      us8 h0, h1;
#pragma unroll
      for (int k = 0; k < 4; ++k) {
        h0[k]   = f2h(a0[k] * L2E);
        h0[k+4] = f2h(a1[k] * L2E);
        h1[k]   = f2h(b0[k] * L2E);
        h1[k+4] = f2h(b1[k] * L2E);
      }
      *(us8*)qd0 = h0;
      *(us8*)qd1 = h1;
    }
    if (loader) { VMCNT3(); }   // K(0) landed; K(1) in flight
    LGKM0();
    SBARRIER();
    SCHED0();
  }

  // ---------------- QK loop: 1 raw barrier/chunk, counted vmcnt only
  f32x4 acc[2][9];
#pragma unroll
  for (int mt = 0; mt < 2; ++mt)
#pragma unroll
    for (int nt = 0; nt < 9; ++nt) acc[mt][nt] = (f32x4){0.f, 0.f, 0.f, 0.f};

#pragma unroll 1
  for (int c = 0; c < 24; ++c) {
    // Q(c+1) loads first (qstagers' auto-wait counts only their own vmem)
    f32x4 a0, a1, b0, b1;
    if (qstager && c < 23) {
      const size_t off = (size_t)(c + 1) * 32;
      a0 = *(const f32x4*)(qsrc0 + off); a1 = *(const f32x4*)(qsrc0 + off + 4);
      b0 = *(const f32x4*)(qsrc1 + off); b1 = *(const f32x4*)(qsrc1 + off + 4);
    }
    SCHED0();
    // K(c+2) prefetch into bufK[(c+2)%3]
    if (loader && c < 22) {
      unsigned char* dst = lds + ((c + 2) % 3) * 36864;
#pragma unroll
      for (int j = 0; j < 3; ++j) {
        const int u = u0 + j;
        gll16(KfB + ((size_t)(u * 24 + c + 2) << 10) + (lane << 4), dst + u * 1024);
      }
    }
    // compute on bufK[c%3], qbuf[c&1]
    const unsigned char* qb = lds + 110592 + (c & 1) * 8192;
    const unsigned char* kb = lds + (c % 3) * 36864;
    h8 qh[2];
#pragma unroll
    for (int mt = 0; mt < 2; ++mt)
      qh[mt] = *(const h8*)(qb + (wq * 2 + mt) * 1024 + lane * 16);
    __builtin_amdgcn_s_setprio(1);
#pragma unroll
    for (int nt = 0; nt < 9; ++nt) {
      const h8 kf = *(const h8*)(kb + (wkv * 9 + nt) * 1024 + lane * 16);
#pragma unroll
      for (int mt = 0; mt < 2; ++mt)
        acc[mt][nt] = __builtin_amdgcn_mfma_f32_16x16x32_f16(qh[mt], kf, acc[mt][nt], 0, 0, 0);
    }
    __builtin_amdgcn_s_setprio(0);
    SCHED0();   // keep cvt + ds_writes after the MFMA cluster
    if (qstager && c < 23) {
      us8 h0, h1;
#pragma unroll
      for (int k = 0; k < 4; ++k) {
        h0[k]   = f2h(a0[k] * L2E);
        h0[k+4] = f2h(a1[k] * L2E);
        h1[k]   = f2h(b0[k] * L2E);
        h1[k+4] = f2h(b1[k] * L2E);
      }
      *(us8*)(qd0 + ((c + 1) & 1) * 8192) = h0;
      *(us8*)(qd1 + ((c + 1) & 1) * 8192) = h1;
    }
    if (loader) {
      if (c <= 21) { VMCNT3(); }   // K(c+1) landed; K(c+2) still in flight
      else         { VMCNT0(); }   // tail drain
    }
    LGKM0();
    SBARRIER();
    SCHED0();
  }

  // ---------------- one-shot softmax (exp2 domain; Q pre-scaled by log2 e)
  float pm[2][4];
#pragma unroll
  for (int mt = 0; mt < 2; ++mt)
#pragma unroll
    for (int i2 = 0; i2 < 4; ++i2) {
      float v = acc[mt][0][i2];
#pragma unroll
      for (int nt = 1; nt < 9; ++nt) v = fmaxf(v, acc[mt][nt][i2]);
      pm[mt][i2] = v;
    }
#pragma unroll
  for (int mk = 1; mk < 16; mk <<= 1)
#pragma unroll
    for (int mt = 0; mt < 2; ++mt)
#pragma unroll
      for (int i2 = 0; i2 < 4; ++i2)
        pm[mt][i2] = fmaxf(pm[mt][i2], __shfl_xor(pm[mt][i2], mk, 64));
  if (ln == 0) {
#pragma unroll
    for (int mt = 0; mt < 2; ++mt)
#pragma unroll
      for (int i2 = 0; i2 < 4; ++i2)
        sRa[wkv][wq * 32 + mt * 16 + g * 4 + i2] = pm[mt][i2];
  }
  __syncthreads();

  float mfin[2][4], ps[2][4];
#pragma unroll
  for (int mt = 0; mt < 2; ++mt)
#pragma unroll
    for (int i2 = 0; i2 < 4; ++i2) {
      const int rw = wq * 32 + mt * 16 + g * 4 + i2;
      mfin[mt][i2] = fmaxf(fmaxf(sRa[0][rw], sRa[1][rw]), fmaxf(sRa[2][rw], sRa[3][rw]));
      ps[mt][i2] = 0.f;
    }
#pragma unroll
  for (int mt = 0; mt < 2; ++mt)
#pragma unroll
    for (int nt = 0; nt < 9; ++nt)
#pragma unroll
      for (int i2 = 0; i2 < 4; ++i2) {
        const float p = exp2f(acc[mt][nt][i2] - mfin[mt][i2]);
        acc[mt][nt][i2] = p;
        ps[mt][i2] += p;
      }
#pragma unroll
  for (int mk = 1; mk < 16; mk <<= 1)
#pragma unroll
    for (int mt = 0; mt < 2; ++mt)
#pragma unroll
      for (int i2 = 0; i2 < 4; ++i2)
        ps[mt][i2] += __shfl_xor(ps[mt][i2], mk, 64);
  if (ln == 0) {
#pragma unroll
    for (int mt = 0; mt < 2; ++mt)
#pragma unroll
      for (int i2 = 0; i2 < 4; ++i2)
        sRb[wkv][wq * 32 + mt * 16 + g * 4 + i2] = ps[mt][i2];
  }
  __syncthreads();

  // normalize P -> swizzled sP (aliases dead bufK/qbuf)
  {
    unsigned short* sPp = (unsigned short*)lds;
#pragma unroll
    for (int mt = 0; mt < 2; ++mt)
#pragma unroll
      for (int i2 = 0; i2 < 4; ++i2) {
        const int rw = wq * 32 + mt * 16 + g * 4 + i2;
        const float inv = 1.0f / ((sRb[0][rw] + sRb[1][rw]) + (sRb[2][rw] + sRb[3][rw]));
#pragma unroll
        for (int nt = 0; nt < 9; ++nt) {
          const int u = wkv * 18 + nt * 2 + (ln >> 3);
          sPp[rw * 576 + ((u ^ (rw & 7)) << 3) + (ln & 7)] = f2h(acc[mt][nt][i2] * inv);
        }
      }
  }
  __syncthreads();

  // ---------------- PV: [64q x 96d]/wave x 2 passes; vf double-buffered (2x unroll)
#pragma unroll 1
  for (int p = 0; p < 2; ++p) {
    f32x4 O[4][3];
#pragma unroll
    for (int mt = 0; mt < 4; ++mt)
#pragma unroll
      for (int nt = 0; nt < 3; ++nt) O[mt][nt] = (f32x4){0.f, 0.f, 0.f, 0.f};

    // dtile base: dt = wd8*6 + p*3 + nt
    const unsigned short* vbase = VfB + ((size_t)(wd8 * 6 + p * 3) << 9) + lane * 8;
    h8 vfA[3], vfB2[3];
#pragma unroll
    for (int nt = 0; nt < 3; ++nt)
      vfA[nt] = *(const h8*)(vbase + ((size_t)nt << 9));

#pragma unroll 1
    for (int kc = 0; kc < 18; kc += 2) {
#pragma unroll
      for (int nt = 0; nt < 3; ++nt)
        vfB2[nt] = *(const h8*)(vbase + ((size_t)((kc + 1) * 48 + nt) << 9));
      {
        h8 pa[4];
#pragma unroll
        for (int mt = 0; mt < 4; ++mt) {
          const int row = wq2 * 64 + mt * 16 + ln;
          const int u = kc * 4 + g;
          pa[mt] = *(const h8*)(lds + row * 1152 + ((u ^ (row & 7)) << 4));
        }
#pragma unroll
        for (int nt = 0; nt < 3; ++nt)
#pragma unroll
          for (int mt = 0; mt < 4; ++mt)
            O[mt][nt] = __builtin_amdgcn_mfma_f32_16x16x32_f16(pa[mt], vfA[nt], O[mt][nt], 0, 0, 0);
      }
      if (kc < 16) {
#pragma unroll
        for (int nt = 0; nt < 3; ++nt)
          vfA[nt] = *(const h8*)(vbase + ((size_t)((kc + 2) * 48 + nt) << 9));
      }
      {
        h8 pa[4];
#pragma unroll
        for (int mt = 0; mt < 4; ++mt) {
          const int row = wq2 * 64 + mt * 16 + ln;
          const int u = (kc + 1) * 4 + g;
          pa[mt] = *(const h8*)(lds + row * 1152 + ((u ^ (row & 7)) << 4));
        }
#pragma unroll
        for (int nt = 0; nt < 3; ++nt)
#pragma unroll
          for (int mt = 0; mt < 4; ++mt)
            O[mt][nt] = __builtin_amdgcn_mfma_f32_16x16x32_f16(pa[mt], vfB2[nt], O[mt][nt], 0, 0, 0);
      }
    }

    float* ob = Out + ((size_t)(b * Nn + q0 + wq2 * 64)) * Dd;
#pragma unroll
    for (int mt = 0; mt < 4; ++mt)
#pragma unroll
      for (int nt = 0; nt < 3; ++nt)
#pragma unroll
        for (int i2 = 0; i2 < 4; ++i2)
          ob[(size_t)(mt * 16 + g * 4 + i2) * Dd + wd8 * 96 + p * 48 + nt * 16 + ln] = O[mt][nt][i2];
  }
}

extern "C" void kernel_launch(void* const* d_in, const int* in_sizes, int n_in,
                              void* d_out, int out_size, void* d_ws, size_t ws_size,
                              hipStream_t stream) {
  const float* Q = (const float*)d_in[0];
  const float* K = (const float*)d_in[1];
  float* Out = (float*)d_out;
  unsigned short* Kf = (unsigned short*)d_ws;
  unsigned short* Vf = Kf + KF_ELEMS;
  fusion_prep<<<dim3(Bb * 18), dim3(256), 0, stream>>>(K, Kf, Vf);
  fusion_main<<<dim3(Bb * 8), dim3(1024), 0, stream>>>(Q, Kf, Vf, Out);
}